// Round 4
// baseline (149.439 us; speedup 1.0000x reference)
//
#include <hip/hip_runtime.h>
#include <math.h>

// ---------------- problem constants ----------------
#define KK     9
#define NCLS   13
#define NANC   5
#define NBB    128
#define NHH    26
#define NWW    26
#define NTT    50
#define LL     21
#define CHC    32
#define NPIX   676
#define NANCHT 3380
#define NCELLT 432640
#define GTS    20     // floats per target in fp32 exact-path table
#define GTH    24     // halves per target in fp16 cull table (48 B, 16B-aligned stride)
#define MWPB   106    // mask words per batch
#define HALFSPLIT 1728 // 27 waves cover [0,1728); slot1 = +1728 (64-aligned)
#define NBLK   27     // grid.x for confmask

// derived float constants
#define LOG2E_F   1.4426950408889634f
#define K1C       2.8853900817779268f   // SHARP*log2e
#define K2C       0.036067376022224085f // K1C/TH
#define SXW       24.615384615384617f   // 640/26
#define SYH       18.461538461538463f   // 480/26
#define THRESH_S  43.500902934225507f   // 9 + SIL*9*(e^2-1)
#define CULL_H    330.0f                // conservative fp16 cull: true cut d*^2=288.25 + fp16 err
#define CONF_T_SCALE 0.017390849194407297f
#define OBJ_W     5.0f
#define EPOCH_PRETRAIN 15
#define BIGV      6.0e18f

typedef _Float16 h2 __attribute__((ext_vector_type(2)));
typedef _Float16 h4 __attribute__((ext_vector_type(4)));
typedef _Float16 h8 __attribute__((ext_vector_type(8)));

static __device__ __forceinline__ float fast_exp2(float x){ return __builtin_amdgcn_exp2f(x); }
static __device__ __forceinline__ float fast_sqrt(float x){ return __builtin_amdgcn_sqrtf(x); }
static __device__ __forceinline__ float sigmoidf_(float x){
  return 1.0f/(1.0f + fast_exp2(-LOG2E_F*x));
}

__constant__ float c_anch[10] = {1.482f,2.2412f,2.0501f,3.1265f,2.3946f,4.6891f,
                                 3.1018f,3.991f,3.4879f,5.8851f};

// ws layout (bytes):
//   [0,4096)         : bc_part  double[NBB][4]
//   [4096,31744)     : partials double[NBLK*NBB]
//   [31744,543744)   : gts_neg  float[NBB*NTT*GTS]  fp32 NEGATED px corners [x0..x8,BIG,y0..y8,BIG]
//   [543744,544256)  : nvalid   int[NBB]
//   [544256,598528)  : maskw    u32[NBB*MWPB]
//   [598528,905728)  : gth      _Float16[NBB*NTT*GTH] fp16 NEGATED px corners
//                        per t: [x0..x7 | y0..y7 | x8,y8 | 6 pad halves]

// ---------------- phase 0: prep ----------------
__global__ __launch_bounds__(64) void prep_kernel(const float* __restrict__ tgt,
                                                  float* __restrict__ gts_neg,
                                                  _Float16* __restrict__ gth,
                                                  int* __restrict__ nvalid){
  int b = blockIdx.x;
  int t = threadIdx.x;
  const float* trow = tgt + (size_t)b*NTT*LL;
  float v1 = (t < NTT) ? trow[t*LL + 1] : 0.0f;
  unsigned long long mk = __ballot(t < NTT && v1 != 0.0f);
  int firstInvalid = __ffsll(~mk) - 1;
  if (t == 0) nvalid[b] = firstInvalid;
  // fp32 table
  for (int idx = t; idx < NTT*GTS; idx += 64){
    int tt = idx / GTS;
    int c  = idx - tt*GTS;
    float v;
    if (c == 9 || c == 19)      v = BIGV;
    else if (c < 9)             v = -(trow[tt*LL + 1 + 2*c] * 640.0f);
    else                        v = -(trow[tt*LL + 2 + 2*(c-10)] * 480.0f);
    gts_neg[(size_t)b*NTT*GTS + idx] = v;
  }
  // fp16 table
  for (int idx = t; idx < NTT*GTH; idx += 64){
    int tt = idx / GTH;
    int c  = idx - tt*GTH;
    float v = 0.0f;
    if (c < 8)        v = -(trow[tt*LL + 1 + 2*c] * 640.0f);      // x0..x7
    else if (c < 16)  v = -(trow[tt*LL + 2 + 2*(c-8)] * 480.0f);  // y0..y7
    else if (c == 16) v = -(trow[tt*LL + 1 + 16] * 640.0f);       // x8
    else if (c == 17) v = -(trow[tt*LL + 2 + 16] * 480.0f);       // y8
    gth[(size_t)b*NTT*GTH + idx] = (_Float16)v;
  }
}

// ---------------- phase A: fp16 packed cull, 2 cells/thread ----------------
__global__ __launch_bounds__(64) void region_confmask_kernel(
    const float* __restrict__ outp, const _Float16* __restrict__ gth,
    const float* __restrict__ gts_neg, const int* __restrict__ nvalid,
    unsigned int* __restrict__ maskw, double* __restrict__ partials){
  int b = blockIdx.y;
  int tid = threadIdx.x;
  int wavebase0 = blockIdx.x * 64;          // 64-aligned, < 1728
  int c0 = wavebase0 + tid;                 // always < 1728 <= NANCHT
  int c1 = c0 + HALFSPLIT;
  bool ok1 = (c1 < NANCHT);

  // stage fp16 gt table (2400 B) -> LDS
  __shared__ int sgt_i[NTT*GTH/2] __attribute__((aligned(16)));
  const int* gsrc = (const int*)(gth + (size_t)b*NTT*GTH);
  for (int idx = tid; idx < NTT*GTH/2; idx += 64) sgt_i[idx] = gsrc[idx];
  __syncthreads();
  const _Float16* sgt = (const _Float16*)sgt_i;

  // per-slot pred corners: fp32 (exact path) + packed fp16 (cull)
  float Pxf0[KK], Pyf0[KK], Pxf1[KK], Pyf1[KK];
  h8 Px8_0, Py8_0, Px8_1, Py8_1;
  h2 Pt_0, Pt_1;
  float cf0 = 0.0f, cf1 = 0.0f;
#pragma unroll
  for (int k = 0; k < KK; ++k){ Pxf1[k] = 0.0f; Pyf1[k] = 0.0f; }

  {
    int a = c0 / NPIX, rem = c0 - a*NPIX;
    int j = rem / NWW, i = rem - j*NWW;
    const float* base = outp + (((size_t)b*NANC + a)*CHC)*NPIX + rem;
#pragma unroll
    for (int k = 0; k < KK; ++k){
      float rx = base[(2*k)*NPIX], ry = base[(2*k+1)*NPIX];
      if (k == 0){ rx = sigmoidf_(rx); ry = sigmoidf_(ry); }
      Pxf0[k] = (rx + (float)i)*SXW; Pyf0[k] = (ry + (float)j)*SYH;
    }
    cf0 = sigmoidf_(base[(2*KK)*NPIX]);
  }
  if (ok1){
    int a = c1 / NPIX, rem = c1 - a*NPIX;
    int j = rem / NWW, i = rem - j*NWW;
    const float* base = outp + (((size_t)b*NANC + a)*CHC)*NPIX + rem;
#pragma unroll
    for (int k = 0; k < KK; ++k){
      float rx = base[(2*k)*NPIX], ry = base[(2*k+1)*NPIX];
      if (k == 0){ rx = sigmoidf_(rx); ry = sigmoidf_(ry); }
      Pxf1[k] = (rx + (float)i)*SXW; Pyf1[k] = (ry + (float)j)*SYH;
    }
    cf1 = sigmoidf_(base[(2*KK)*NPIX]);
  }
#pragma unroll
  for (int k = 0; k < 8; ++k){
    Px8_0[k] = (_Float16)Pxf0[k]; Py8_0[k] = (_Float16)Pyf0[k];
    Px8_1[k] = (_Float16)Pxf1[k]; Py8_1[k] = (_Float16)Pyf1[k];
  }
  Pt_0 = (h2){(_Float16)Pxf0[8], (_Float16)Pyf0[8]};
  Pt_1 = (h2){(_Float16)Pxf1[8], (_Float16)Pyf1[8]};

  const _Float16 TH16 = (_Float16)CULL_H;
  int nv = nvalid[b];
  unsigned long long q0 = 0ull, q1 = 0ull;
#pragma unroll 2
  for (int t = 0; t < nv; ++t){
    h8 GX = *(const h8*)(sgt + t*GTH);        // ds_read_b128 (broadcast)
    h8 GY = *(const h8*)(sgt + t*GTH + 8);    // ds_read_b128
    h2 GT = *(const h2*)(sgt + t*GTH + 16);   // ds_read_b32
    unsigned long long bit = 1ull << t;
    {
      h8 dx = Px8_0 + GX, dy = Py8_0 + GY;
      h8 r  = __builtin_elementwise_fma(dy, dy, dx*dx);
      h4 r4 = __builtin_elementwise_min(__builtin_shufflevector(r, r, 0,1,2,3),
                                        __builtin_shufflevector(r, r, 4,5,6,7));
      h2 r2 = __builtin_elementwise_min(__builtin_shufflevector(r4, r4, 0,1),
                                        __builtin_shufflevector(r4, r4, 2,3));
      h2 dt = Pt_0 + GT; h2 rt = dt*dt;
      _Float16 m = __builtin_elementwise_min(
          __builtin_elementwise_min(r2[0], r2[1]), (_Float16)(rt[0] + rt[1]));
      if (m < TH16) q0 |= bit;
    }
    {
      h8 dx = Px8_1 + GX, dy = Py8_1 + GY;
      h8 r  = __builtin_elementwise_fma(dy, dy, dx*dx);
      h4 r4 = __builtin_elementwise_min(__builtin_shufflevector(r, r, 0,1,2,3),
                                        __builtin_shufflevector(r, r, 4,5,6,7));
      h2 r2 = __builtin_elementwise_min(__builtin_shufflevector(r4, r4, 0,1),
                                        __builtin_shufflevector(r4, r4, 2,3));
      h2 dt = Pt_1 + GT; h2 rt = dt*dt;
      _Float16 m = __builtin_elementwise_min(
          __builtin_elementwise_min(r2[0], r2[1]), (_Float16)(rt[0] + rt[1]));
      if (m < TH16) q1 |= bit;
    }
  }
  if (!ok1) q1 = 0ull;

  int m0_0 = 1, m0_1 = 1;
  if (__any((q0 | q1) != 0ull)){
    const float* gbase = gts_neg + (size_t)b*NTT*GTS;
    bool e0 = false, e1 = false;
    while (q0){
      int t = __ffsll((long long)q0) - 1; q0 &= q0 - 1;
      const float* gg = gbase + t*GTS;
      float s = 0.0f;
#pragma unroll
      for (int k = 0; k < KK; ++k){
        float dx = Pxf0[k] + gg[k], dy = Pyf0[k] + gg[10+k];
        float d  = fast_sqrt(fmaf(dy, dy, dx*dx));
        float e  = fast_exp2(fmaf(d, -K2C, K1C));
        s += fmaxf(e, 1.0f);
      }
      e0 |= (s > THRESH_S);
    }
    while (q1){
      int t = __ffsll((long long)q1) - 1; q1 &= q1 - 1;
      const float* gg = gbase + t*GTS;
      float s = 0.0f;
#pragma unroll
      for (int k = 0; k < KK; ++k){
        float dx = Pxf1[k] + gg[k], dy = Pyf1[k] + gg[10+k];
        float d  = fast_sqrt(fmaf(dy, dy, dx*dx));
        float e  = fast_exp2(fmaf(d, -K2C, K1C));
        s += fmaxf(e, 1.0f);
      }
      e1 |= (s > THRESH_S);
    }
    if (e0) m0_0 = 0;
    if (e1) m0_1 = 0;
  }

  float contrib = (m0_0 ? 0.5f*cf0*cf0 : 0.0f) + ((ok1 && m0_1) ? 0.5f*cf1*cf1 : 0.0f);

  // bit-packed mask writes (slot0 words [0,54), slot1 words [54,106))
  int lane = tid;
  unsigned long long mb0 = __ballot(m0_0 != 0);
  if ((lane & 31) == 0){
    unsigned int w = (lane == 0) ? (unsigned int)mb0 : (unsigned int)(mb0 >> 32);
    maskw[(size_t)b*MWPB + (wavebase0 >> 5) + (lane >> 5)] = w;
  }
  unsigned long long mb1 = __ballot(m0_1 != 0);
  int wavebase1 = wavebase0 + HALFSPLIT;
  if ((lane & 31) == 0 && wavebase1 < NANCHT){
    unsigned int w = (lane == 0) ? (unsigned int)mb1 : (unsigned int)(mb1 >> 32);
    maskw[(size_t)b*MWPB + (wavebase1 >> 5) + (lane >> 5)] = w;
  }

  // wave reduce contrib -> one double per block
#pragma unroll
  for (int o = 32; o > 0; o >>= 1) contrib += __shfl_xor(contrib, o, 64);
  if (tid == 0) partials[b*NBLK + blockIdx.x] = (double)contrib;
}

// ---------------- phase B+C: scatter winners + small losses ----------------
__global__ __launch_bounds__(64) void scatter_loss_kernel(
    const float* __restrict__ outp, const float* __restrict__ tgt,
    const int* __restrict__ nvalid, const unsigned int* __restrict__ maskw,
    double* __restrict__ bc_part){
  int b = blockIdx.x;
  int t = threadIdx.x;
  __shared__ int keys[NTT];
  int nv = nvalid[b];
  bool valid = (t < nv);

  int key = -1, gi0 = 0, gj0 = 0, bn = 0;
  float txv[KK], tyv[KK];
  float conf_t = 0.0f, tcls = 0.0f;

  if (t < NTT){
    const float* trow = tgt + ((size_t)b*NTT + t)*LL;
    tcls = trow[0];
    float gx0 = trow[1]*(float)NWW;
    float gy0 = trow[2]*(float)NHH;
    gi0 = min(max((int)floorf(gx0), 0), NWW-1);
    gj0 = min(max((int)floorf(gy0), 0), NHH-1);
#pragma unroll
    for (int k = 0; k < KK; ++k){
      txv[k] = trow[1+2*k]*(float)NWW - (float)gi0;
      tyv[k] = trow[2+2*k]*(float)NHH - (float)gj0;
    }
    float gw = trow[LL-2]*(float)NWW, gh = trow[LL-1]*(float)NHH;
    float best = -1.0f;
    for (int a = 0; a < NANC; ++a){
      float aw = c_anch[2*a], ah = c_anch[2*a+1];
      float inter = fminf(aw, gw) * fminf(ah, gh);
      float iou = inter / (aw*ah + gw*gh - inter);
      if (iou > best){ best = iou; bn = a; }
    }
    key = bn*NPIX + gj0*NWW + gi0;
    keys[t] = key;

    long f = (long)b*NANCHT - NPIX + gj0*NWW + gi0;
    if (f < 0) f += NCELLT;
    int bb  = (int)(f / NANCHT);
    int rr  = (int)(f - (long)bb*NANCHT);
    int aa  = rr / NPIX;
    int rr2 = rr - aa*NPIX;
    int jj  = rr2 / NWW;
    int ii  = rr2 - jj*NWW;
    const float* pbase = outp + (((size_t)bb*NANC + aa)*CHC)*NPIX + rr2;
    float s = 0.0f;
#pragma unroll
    for (int k = 0; k < KK; ++k){
      float rx = pbase[(2*k)*NPIX], ry = pbase[(2*k+1)*NPIX];
      if (k == 0){ rx = sigmoidf_(rx); ry = sigmoidf_(ry); }
      float Pxx = (rx + (float)ii)*SXW, Pyy = (ry + (float)jj)*SYH;
      float dx = Pxx - trow[1+2*k]*640.0f;
      float dy = Pyy - trow[2+2*k]*480.0f;
      float d  = fast_sqrt(fmaf(dy, dy, dx*dx));
      float e  = fast_exp2(fmaf(d, -K2C, K1C));
      s += fmaxf(e, 1.0f);
    }
    conf_t = (s - 9.0f) * CONF_T_SCALE;
  }
  __syncthreads();

  bool winner = valid;
  if (valid){
    for (int u = t+1; u < nv; ++u) if (keys[u] == key){ winner = false; break; }
  }

  double lx = 0.0, ly = 0.0, lcls = 0.0, lcf = 0.0;
  if (winner){
    const float* cbase = outp + (((size_t)b*NANC + bn)*CHC)*NPIX + gj0*NWW + gi0;
    float sx = 0.0f, sy = 0.0f;
#pragma unroll
    for (int k = 0; k < KK; ++k){
      float rx = cbase[(2*k)*NPIX], ry = cbase[(2*k+1)*NPIX];
      if (k == 0){ rx = sigmoidf_(rx); ry = sigmoidf_(ry); }
      float dx = rx - txv[k], dy = ry - tyv[k];
      sx = fmaf(dx, dx, sx); sy = fmaf(dy, dy, sy);
    }
    lx = 0.5*(double)sx; ly = 0.5*(double)sy;

    float lg[NCLS], mx = -1e30f;
#pragma unroll
    for (int c = 0; c < NCLS; ++c){ lg[c] = cbase[(2*KK+1+c)*NPIX]; mx = fmaxf(mx, lg[c]); }
    float se = 0.0f;
#pragma unroll
    for (int c = 0; c < NCLS; ++c) se += fast_exp2((lg[c]-mx)*LOG2E_F);
    int label = min(max((int)tcls, 0), NCLS-1);
    lcls = (double)(mx + logf(se) - lg[label]);

    float cf = sigmoidf_(cbase[(2*KK)*NPIX]);
    int idx = bn*NPIX + gj0*NWW + gi0;
    int m0 = (maskw[(size_t)b*MWPB + (idx >> 5)] >> (idx & 31)) & 1;
    float dcf = cf - conf_t;
    lcf = 0.5*OBJ_W*(double)(dcf*dcf) - (m0 ? 0.5*(double)(cf*cf) : 0.0);
  }

#pragma unroll
  for (int o = 32; o > 0; o >>= 1){
    lx  += __shfl_xor(lx,  o, 64);
    ly  += __shfl_xor(ly,  o, 64);
    lcls+= __shfl_xor(lcls,o, 64);
    lcf += __shfl_xor(lcf, o, 64);
  }
  if (threadIdx.x == 0){
    double* bp = bc_part + (size_t)b*4;
    bp[0] = lx; bp[1] = ly; bp[2] = lcls; bp[3] = lcf;
  }
}

// ---------------- finalize ----------------
__global__ __launch_bounds__(256) void finalize_kernel(
    const double* __restrict__ bc_part, const double* __restrict__ partials,
    const int* __restrict__ epoch_p, float* __restrict__ outv){
  int tid = threadIdx.x;
  double vx=0, vy=0, vc=0, vf=0, vb=0;
  for (int i = tid; i < NBB; i += 256){
    vx += bc_part[4*i]; vy += bc_part[4*i+1];
    vc += bc_part[4*i+2]; vf += bc_part[4*i+3];
  }
  for (int i = tid; i < NBLK*NBB; i += 256) vb += partials[i];
#pragma unroll
  for (int o = 32; o > 0; o >>= 1){
    vx += __shfl_xor(vx, o, 64); vy += __shfl_xor(vy, o, 64);
    vc += __shfl_xor(vc, o, 64); vf += __shfl_xor(vf, o, 64);
    vb += __shfl_xor(vb, o, 64);
  }
  __shared__ double sm[5][4];
  int wid = tid >> 6, lane = tid & 63;
  if (lane == 0){ sm[0][wid]=vx; sm[1][wid]=vy; sm[2][wid]=vc; sm[3][wid]=vf; sm[4][wid]=vb; }
  __syncthreads();
  if (tid == 0){
    double fx=0, fy=0, fc=0, ff=0, fb=0;
    for (int w = 0; w < 4; ++w){ fx+=sm[0][w]; fy+=sm[1][w]; fc+=sm[2][w]; ff+=sm[3][w]; fb+=sm[4][w]; }
    double loss = fx + fy + fc;
    if (*epoch_p > EPOCH_PRETRAIN) loss += ff + fb;
    outv[0] = (float)loss;
  }
}

extern "C" void kernel_launch(void* const* d_in, const int* in_sizes, int n_in,
                              void* d_out, int out_size, void* d_ws, size_t ws_size,
                              hipStream_t stream){
  (void)in_sizes; (void)n_in; (void)out_size; (void)ws_size;
  const float* outp = (const float*)d_in[0];
  const float* tgt  = (const float*)d_in[1];
  const int*   ep   = (const int*)d_in[2];
  float* outv = (float*)d_out;
  char* ws = (char*)d_ws;

  double* bc_part   = (double*)(ws);                    // 4096 B
  double* partials  = (double*)(ws + 4096);             // 27648 B
  float*  gts_neg   = (float*) (ws + 31744);            // 512000 B
  int*    nvalid    = (int*)   (ws + 543744);           // 512 B
  unsigned int* maskw = (unsigned int*)(ws + 544256);   // 54272 B
  _Float16* gth     = (_Float16*)(ws + 598528);         // 307200 B

  prep_kernel<<<dim3(NBB), dim3(64), 0, stream>>>(tgt, gts_neg, gth, nvalid);
  region_confmask_kernel<<<dim3(NBLK, NBB), dim3(64), 0, stream>>>(outp, gth, gts_neg, nvalid, maskw, partials);
  scatter_loss_kernel<<<dim3(NBB), dim3(64), 0, stream>>>(outp, tgt, nvalid, maskw, bc_part);
  finalize_kernel<<<dim3(1), dim3(256), 0, stream>>>(bc_part, partials, ep, outv);
}